// Round 5
// baseline (152.932 us; speedup 1.0000x reference)
//
#include <hip/hip_runtime.h>

#define NROWS 8192
#define KDIM  512

typedef __attribute__((ext_vector_type(8))) short bf16x8;   // 8 bf16 = 4 VGPRs
typedef __attribute__((ext_vector_type(4))) float f32x4;

typedef unsigned int u32;
typedef unsigned short u16;

// ---- round-to-nearest-even f32 -> bf16 (bits) ----
__device__ __forceinline__ u16 f2bf(float f) {
    u32 u = __float_as_uint(f);
    u32 rounding = 0x7FFFu + ((u >> 16) & 1u);
    return (u16)((u + rounding) >> 16);
}

// ---- async global->LDS, 16B per lane (wave-uniform base + lane*16) ----
__device__ __forceinline__ void gload_lds16(const void* g, void* l) {
    __builtin_amdgcn_global_load_lds(
        (const __attribute__((address_space(1))) u32*)g,
        (__attribute__((address_space(3))) u32*)l,
        16, 0, 0);
}

// =====================================================================
// Kernel 1: row-normalize (f32) -> bf16. One wave per row, 4 rows/block.
// =====================================================================
__global__ __launch_bounds__(256) void norm_cast_kernel(
        const float* __restrict__ x1, const float* __restrict__ x2,
        u16* __restrict__ o1, u16* __restrict__ o2) {
    const int wave = threadIdx.x >> 6;
    const int lane = threadIdx.x & 63;
    int row = blockIdx.x * 4 + wave;          // 0..16383

    const float* src;
    u16* dst;
    if (row < NROWS) { src = x1 + (size_t)row * KDIM;           dst = o1 + (size_t)row * KDIM; }
    else             { src = x2 + (size_t)(row - NROWS) * KDIM; dst = o2 + (size_t)(row - NROWS) * KDIM; }

    const float4* s4 = (const float4*)src + lane * 2;
    float4 a = s4[0];
    float4 b = s4[1];

    float ss = a.x*a.x + a.y*a.y + a.z*a.z + a.w*a.w
             + b.x*b.x + b.y*b.y + b.z*b.z + b.w*b.w;
    #pragma unroll
    for (int off = 32; off; off >>= 1) ss += __shfl_xor(ss, off);

    float inv = 1.0f / fmaxf(sqrtf(ss), 1e-8f);

    u16 h[8];
    h[0] = f2bf(a.x * inv); h[1] = f2bf(a.y * inv);
    h[2] = f2bf(a.z * inv); h[3] = f2bf(a.w * inv);
    h[4] = f2bf(b.x * inv); h[5] = f2bf(b.y * inv);
    h[6] = f2bf(b.z * inv); h[7] = f2bf(b.w * inv);

    uint4 o;
    o.x = (u32)h[0] | ((u32)h[1] << 16);
    o.y = (u32)h[2] | ((u32)h[3] << 16);
    o.z = (u32)h[4] | ((u32)h[5] << 16);
    o.w = (u32)h[6] | ((u32)h[7] << 16);
    *((uint4*)dst + lane) = o;
}

// =====================================================================
// Kernel 2: 128x256 tile, BK=64, 8 waves (2M x 4N, wave-tile 64x64),
// 8-phase schedule (4 quad-phases per K-tile), counted vmcnt(4),
// st XOR-swizzle, setprio. Grid 2048 -> 8 rounds; per-round C-writes
// 33.5 MB ~ L2 so drains overlap the next round's compute.
//
// LDS 96 KiB: buf{0,1} x { A: 128 rows x 128B @ +0, B: 256 x 128B @ +16384 }
// (row, colbyte c) at row*128 + (c ^ ((row&7)<<4)) via linear gload dest +
// inverse-swizzled global source (both-sides rule).
//
// Staging units per K-tile t: PH1 other.A <- t+1 (2 ops);
// PH2 own.Bg0 <- t+2; PH3 own.Bg1 <- t+2. At PH4: target = t+1 complete
// (last piece = PH1's A); newer = PH2+PH3 = 4 ops -> vmcnt(4).
// =====================================================================

__global__ __launch_bounds__(512, 2) void gemm_bt_kernel(
        const u16* __restrict__ A, const u16* __restrict__ B,
        float* __restrict__ C) {
    __shared__ __align__(1024) char lds[98304];

    // bijective XCD swizzle (nwg = 2048, divisible by 8)
    const int nwg = gridDim.x;
    const int bid = blockIdx.x;
    const int wg  = (bid & 7) * (nwg >> 3) + (bid >> 3);
    const int tile_m = (wg >> 5) << 7;    // 64 m-tiles of 128
    const int tile_n = (wg & 31) << 8;    // 32 n-tiles of 256

    const int tid  = threadIdx.x;
    const int wid  = tid >> 6;
    const int lane = tid & 63;
    const int wm   = wid >> 2;      // 0..1  (M halves of 128)
    const int wn   = wid & 3;       // 0..3  (N quarters of 256)
    const int fr   = lane & 15;
    const int q    = lane >> 4;

    // staging constants
    const int s_rl0 = tid >> 3;           // 0..63
    const int s_cl  = (tid & 7) << 4;     // 0..112

    // ds-read constants
    const int xr     = (fr & 7) << 4;
    const int colsw0 = (q * 16) ^ xr;          // kk=0 fragment col (swizzled)
    const int colsw1 = (64 + q * 16) ^ xr;     // kk=1

    f32x4  acc[4][4] = {};
    bf16x8 af[2][2];   // current A MH-half (2 m-frags x 2 kk)
    bf16x8 bf[4][2];   // full B wave-tile (4 n-frags x 2 kk)

#define ABUF(b) (lds + (b) * 49152)
#define BBUF(b) (lds + (b) * 49152 + 16384)
#define BAR()   __builtin_amdgcn_s_barrier()
#define LGKM0() asm volatile("s_waitcnt lgkmcnt(0)")
#define VM4()   asm volatile("s_waitcnt vmcnt(4)" ::: "memory")
#define VM0()   asm volatile("s_waitcnt vmcnt(0)" ::: "memory")

// stage full A tile (128 rows x 128B = 16KB, 2 ops/thread) of K-tile T
#define STAGE_A(b, T) do {                                                     \
    char* _l = ABUF(b);                                                        \
    _Pragma("unroll")                                                          \
    for (int _it = 0; _it < 2; ++_it) {                                        \
        int _row = _it * 64 + s_rl0;                                           \
        int _csrc = s_cl ^ ((_row & 7) << 4);                                  \
        gload_lds16((const char*)A + (size_t)(tile_m + _row) * (KDIM * 2)      \
                        + ((T) * 128) + _csrc,                                 \
                    _l + _row * 128 + s_cl);                                   \
    }                                                                          \
} while (0)

// stage B group G (128 rows with bit5==G, 2 ops/thread) of K-tile T
#define STAGE_B(b, G, T) do {                                                  \
    char* _l = BBUF(b);                                                        \
    _Pragma("unroll")                                                          \
    for (int _it = 0; _it < 2; ++_it) {                                        \
        int _rl  = _it * 64 + s_rl0;                                           \
        int _row = ((_rl >> 5) << 6) + (G) * 32 + (_rl & 31);                  \
        int _csrc = s_cl ^ ((_row & 7) << 4);                                  \
        gload_lds16((const char*)B + (size_t)(tile_n + _row) * (KDIM * 2)      \
                        + ((T) * 128) + _csrc,                                 \
                    _l + _row * 128 + s_cl);                                   \
    }                                                                          \
} while (0)

#define LOAD_A(b, MH) do {                                                     \
    _Pragma("unroll")                                                          \
    for (int _m = 0; _m < 2; ++_m) {                                           \
        char* _p = ABUF(b) + (wm * 64 + (MH) * 32 + _m * 16 + fr) * 128;       \
        af[_m][0] = *(const bf16x8*)(_p + colsw0);                             \
        af[_m][1] = *(const bf16x8*)(_p + colsw1);                             \
    }                                                                          \
} while (0)

#define LOAD_B(b, NH) do {                                                     \
    _Pragma("unroll")                                                          \
    for (int _n = 0; _n < 2; ++_n) {                                           \
        char* _p = BBUF(b) + (wn * 64 + (NH) * 32 + _n * 16 + fr) * 128;       \
        bf[(NH) * 2 + _n][0] = *(const bf16x8*)(_p + colsw0);                  \
        bf[(NH) * 2 + _n][1] = *(const bf16x8*)(_p + colsw1);                  \
    }                                                                          \
} while (0)

#define MFMA_Q(MH, NH) do {                                                    \
    __builtin_amdgcn_s_setprio(1);                                             \
    _Pragma("unroll")                                                          \
    for (int _m = 0; _m < 2; ++_m)                                             \
    _Pragma("unroll")                                                          \
    for (int _n = 0; _n < 2; ++_n)                                             \
    _Pragma("unroll")                                                          \
    for (int _kk = 0; _kk < 2; ++_kk)                                          \
        acc[(MH) * 2 + _m][(NH) * 2 + _n] = __builtin_amdgcn_mfma_f32_16x16x32_bf16( \
            af[_m][_kk], bf[(NH) * 2 + _n][_kk], acc[(MH) * 2 + _m][(NH) * 2 + _n], 0, 0, 0); \
    __builtin_amdgcn_s_setprio(0);                                             \
} while (0)

    // ---- prologue: tile0 (A,Bg0,Bg1) + tile1 (Bg0,Bg1) = 10 ops ----
    STAGE_A(0, 0); STAGE_B(0, 0, 0); STAGE_B(0, 1, 0);
    STAGE_B(1, 0, 1); STAGE_B(1, 1, 1);
    VM4();   // tile0 complete (4 newer: tile1's B ops)
    BAR();

    // ---- main: 3 iterations x 2 tiles = tiles 0..5, staging thru 7 ----
    for (int i = 0; i < 3; ++i) {
        const int t0 = 2 * i, t1 = 2 * i + 1;
        // tile t0 (buf0)
        LOAD_A(0, 0); LOAD_B(0, 0);
        STAGE_A(1, t0 + 1);                    // buf1.A <- tile t0+1
        BAR(); LGKM0(); MFMA_Q(0, 0); BAR();
        LOAD_B(0, 1);
        STAGE_B(0, 0, t0 + 2);                 // buf0.Bg0 <- tile t0+2
        BAR(); LGKM0(); MFMA_Q(0, 1); BAR();
        LOAD_A(0, 1);
        STAGE_B(0, 1, t0 + 2);                 // buf0.Bg1
        BAR(); LGKM0(); MFMA_Q(1, 1); BAR();
        VM4();                                 // tile t0+1 complete
        BAR(); MFMA_Q(1, 0); BAR();
        // tile t1 (buf1)
        LOAD_A(1, 0); LOAD_B(1, 0);
        STAGE_A(0, t1 + 1);                    // buf0.A <- tile t1+1
        BAR(); LGKM0(); MFMA_Q(0, 0); BAR();
        LOAD_B(1, 1);
        STAGE_B(1, 0, t1 + 2);                 // buf1.Bg0 <- tile t1+2
        BAR(); LGKM0(); MFMA_Q(0, 1); BAR();
        LOAD_A(1, 1);
        STAGE_B(1, 1, t1 + 2);                 // buf1.Bg1
        BAR(); LGKM0(); MFMA_Q(1, 1); BAR();
        VM4();                                 // tile t1+1 complete
        BAR(); MFMA_Q(1, 0); BAR();
    }

    // ---- tail: tiles 6 (buf0) and 7 (buf1) ----
    LOAD_A(0, 0); LOAD_B(0, 0);
    STAGE_A(1, 7);                             // last stage op
    BAR(); LGKM0(); MFMA_Q(0, 0); BAR();
    LOAD_B(0, 1);
    BAR(); LGKM0(); MFMA_Q(0, 1); BAR();
    LOAD_A(0, 1);
    BAR(); LGKM0(); MFMA_Q(1, 1); BAR();
    VM0();                                     // tile 7 complete
    BAR(); MFMA_Q(1, 0); BAR();
    LOAD_A(1, 0); LOAD_B(1, 0);
    BAR(); LGKM0(); MFMA_Q(0, 0); BAR();
    LOAD_B(1, 1);
    BAR(); LGKM0(); MFMA_Q(0, 1); BAR();
    LOAD_A(1, 1);
    BAR(); LGKM0(); MFMA_Q(1, 1); BAR();
    MFMA_Q(1, 0);

    // ---- epilogue: D mapping n = lane&15, m = (lane>>4)*4 + reg ----
    #pragma unroll
    for (int mf = 0; mf < 4; ++mf) {
        #pragma unroll
        for (int nf = 0; nf < 4; ++nf) {
            size_t base = (size_t)(tile_m + wm * 64 + mf * 16 + q * 4) * NROWS
                        + (size_t)(tile_n + wn * 64 + nf * 16 + fr);
            #pragma unroll
            for (int r = 0; r < 4; ++r)
                C[base + (size_t)r * NROWS] = 16.0f * acc[mf][nf][r];
        }
    }

#undef ABUF
#undef BBUF
#undef BAR
#undef LGKM0
#undef VM4
#undef VM0
#undef STAGE_A
#undef STAGE_B
#undef LOAD_A
#undef LOAD_B
#undef MFMA_Q
}

extern "C" void kernel_launch(void* const* d_in, const int* in_sizes, int n_in,
                              void* d_out, int out_size, void* d_ws, size_t ws_size,
                              hipStream_t stream) {
    const float* x1 = (const float*)d_in[0];
    const float* x2 = (const float*)d_in[1];
    float* out = (float*)d_out;

    u16* a_bf = (u16*)d_ws;                          // 8 MB
    u16* b_bf = a_bf + (size_t)NROWS * KDIM;         // 8 MB

    norm_cast_kernel<<<4096, 256, 0, stream>>>(x1, x2, a_bf, b_bf);

    const int grid = (NROWS / 128) * (NROWS / 256);  // 2048
    gemm_bt_kernel<<<grid, 512, 0, stream>>>(a_bf, b_bf, out);
}

// Round 7
// 134.521 us; speedup vs baseline: 1.1369x; 1.1369x over previous
//
#include <hip/hip_runtime.h>

#define NROWS 8192
#define KDIM  512

typedef __attribute__((ext_vector_type(8))) short bf16x8;   // 8 bf16 = 4 VGPRs
typedef __attribute__((ext_vector_type(4))) float f32x4;
typedef __attribute__((ext_vector_type(4))) u_int32_t u32x4;

typedef unsigned int u32;
typedef unsigned short u16;

// ---- round-to-nearest-even f32 -> bf16 (bits) ----
__device__ __forceinline__ u16 f2bf(float f) {
    u32 u = __float_as_uint(f);
    u32 rounding = 0x7FFFu + ((u >> 16) & 1u);
    return (u16)((u + rounding) >> 16);
}

// ---- async global->LDS, 16B per lane (wave-uniform base + lane*16) ----
__device__ __forceinline__ void gload_lds16(const void* g, void* l) {
    __builtin_amdgcn_global_load_lds(
        (const __attribute__((address_space(1))) u32*)g,
        (__attribute__((address_space(3))) u32*)l,
        16, 0, 0);
}

// =====================================================================
// Kernel 1: row-normalize (f32) -> bf16 scaled by 4 (= sqrt(16), exact
// power of two so bf16 rounding identical). One wave per row.
// Inputs are read once ever -> nontemporal loads (don't pollute L2/L3;
// the caches must stay free for the GEMM's bf16 operands + C stream).
// =====================================================================
__global__ __launch_bounds__(256) void norm_cast_kernel(
        const float* __restrict__ x1, const float* __restrict__ x2,
        u16* __restrict__ o1, u16* __restrict__ o2) {
    const int wave = threadIdx.x >> 6;
    const int lane = threadIdx.x & 63;
    int row = blockIdx.x * 4 + wave;          // 0..16383

    const float* src;
    u16* dst;
    if (row < NROWS) { src = x1 + (size_t)row * KDIM;           dst = o1 + (size_t)row * KDIM; }
    else             { src = x2 + (size_t)(row - NROWS) * KDIM; dst = o2 + (size_t)(row - NROWS) * KDIM; }

    const f32x4* s4 = (const f32x4*)src + lane * 2;
    f32x4 a = __builtin_nontemporal_load(s4);
    f32x4 b = __builtin_nontemporal_load(s4 + 1);

    float ss = a.x*a.x + a.y*a.y + a.z*a.z + a.w*a.w
             + b.x*b.x + b.y*b.y + b.z*b.z + b.w*b.w;
    #pragma unroll
    for (int off = 32; off; off >>= 1) ss += __shfl_xor(ss, off);

    // 4/||x||  (keep eps clamp for exact reference semantics)
    float inv = 4.0f / fmaxf(sqrtf(ss), 1e-8f);

    u16 h[8];
    h[0] = f2bf(a.x * inv); h[1] = f2bf(a.y * inv);
    h[2] = f2bf(a.z * inv); h[3] = f2bf(a.w * inv);
    h[4] = f2bf(b.x * inv); h[5] = f2bf(b.y * inv);
    h[6] = f2bf(b.z * inv); h[7] = f2bf(b.w * inv);

    uint4 o;
    o.x = (u32)h[0] | ((u32)h[1] << 16);
    o.y = (u32)h[2] | ((u32)h[3] << 16);
    o.z = (u32)h[4] | ((u32)h[5] << 16);
    o.w = (u32)h[6] | ((u32)h[7] << 16);
    *((uint4*)dst + lane) = o;   // normal store: this IS the GEMM input, keep cached
}

// =====================================================================
// Kernel 2: R2-verified 256x256 tile, BK=64, 8 waves (2Mx4N), 8-phase
// schedule, counted vmcnt(6), st XOR-swizzle, setprio.
// ONLY change vs R2: C stores are NONTEMPORAL (bypass L2/L3) so the
// 268 MB write stream stops thrashing the Infinity Cache and the bf16
// inputs stay cache-resident for staging. Scale pre-folded (4x per side).
// =====================================================================

__global__ __launch_bounds__(512, 2) void gemm_bt_kernel(
        const u16* __restrict__ A, const u16* __restrict__ B,
        float* __restrict__ C) {
    __shared__ __align__(1024) char lds[131072];

    // bijective XCD swizzle (nwg = 1024, divisible by 8)
    const int nwg = gridDim.x;
    const int bid = blockIdx.x;
    const int wg  = (bid & 7) * (nwg >> 3) + (bid >> 3);
    const int tile_m = (wg >> 5) << 8;
    const int tile_n = (wg & 31) << 8;

    const int tid  = threadIdx.x;
    const int wid  = tid >> 6;
    const int lane = tid & 63;
    const int wm   = wid >> 2;      // 0..1  (M)
    const int wn   = wid & 3;       // 0..3  (N)
    const int fr   = lane & 15;
    const int q    = lane >> 4;

    // staging constants: thread tid covers LDS bytes it*8192 + tid*16
    const int s_rl0 = tid >> 3;           // 0..63
    const int s_cl  = (tid & 7) << 4;     // 0..112

    // ds-read constants
    const int xr     = (fr & 7) << 4;
    const int colsw0 = (q * 16) ^ xr;          // kk=0 fragment col (swizzled)
    const int colsw1 = (64 + q * 16) ^ xr;     // kk=1
    const int aRow   = ((wm << 7) + fr) << 7;            // byte row base in A region
    const int bRow   = (((wn << 6) + fr) << 7) + 32768;  // byte row base in B region

    f32x4  acc[8][4] = {};
    bf16x8 af[4][2];   // current A half (4 mi x 2 kk)
    bf16x8 bf[4][2];   // full B tile   (4 ni x 2 kk)

// stage one half-group: ISB selects A/B, BUF buffer, G group bit, T K-tile idx
#define STAGE(ISB, BUF, G, T) do {                                             \
    const u16* _g  = (ISB) ? B : A;                                            \
    const int _grow = (ISB) ? tile_n : tile_m;                                 \
    char* _l = lds + (BUF) * 65536 + ((ISB) ? 32768 : 0);                      \
    _Pragma("unroll")                                                          \
    for (int _it = 0; _it < 2; ++_it) {                                        \
        int _rl  = _it * 64 + s_rl0;                                           \
        int _row = (ISB) ? (((_rl >> 5) << 6) + ((G) << 5) + (_rl & 31))       \
                         : (((_rl >> 6) << 7) + ((G) << 6) + (_rl & 63));      \
        int _csrc = s_cl ^ ((_row & 7) << 4);                                  \
        gload_lds16((const char*)_g + ((size_t)(_grow + _row) * KDIM + (size_t)(T) * 64) * 2 + _csrc, \
                    _l + _row * 128 + s_cl);                                   \
    }                                                                          \
} while (0)

#define LOAD_A(BUF, MH) do {                                                   \
    char* _l = lds + (BUF) * 65536;                                            \
    _Pragma("unroll")                                                          \
    for (int _m = 0; _m < 4; ++_m) {                                           \
        af[_m][0] = *(const bf16x8*)(_l + aRow + ((MH) * 4 + _m) * 2048 + colsw0); \
        af[_m][1] = *(const bf16x8*)(_l + aRow + ((MH) * 4 + _m) * 2048 + colsw1); \
    }                                                                          \
} while (0)

#define LOAD_B(BUF, NH) do {                                                   \
    char* _l = lds + (BUF) * 65536;                                            \
    _Pragma("unroll")                                                          \
    for (int _n = 0; _n < 2; ++_n) {                                           \
        bf[(NH) * 2 + _n][0] = *(const bf16x8*)(_l + bRow + ((NH) * 2 + _n) * 2048 + colsw0); \
        bf[(NH) * 2 + _n][1] = *(const bf16x8*)(_l + bRow + ((NH) * 2 + _n) * 2048 + colsw1); \
    }                                                                          \
} while (0)

#define MFMA_Q(MH, NH) do {                                                    \
    __builtin_amdgcn_s_setprio(1);                                             \
    _Pragma("unroll")                                                          \
    for (int _m = 0; _m < 4; ++_m)                                             \
    _Pragma("unroll")                                                          \
    for (int _n = 0; _n < 2; ++_n)                                             \
    _Pragma("unroll")                                                          \
    for (int _kk = 0; _kk < 2; ++_kk)                                          \
        acc[(MH) * 4 + _m][(NH) * 2 + _n] = __builtin_amdgcn_mfma_f32_16x16x32_bf16( \
            af[_m][_kk], bf[(NH) * 2 + _n][_kk], acc[(MH) * 4 + _m][(NH) * 2 + _n], 0, 0, 0); \
    __builtin_amdgcn_s_setprio(0);                                             \
} while (0)

#define BAR()   __builtin_amdgcn_s_barrier()
#define LGKM0() asm volatile("s_waitcnt lgkmcnt(0)")

    // ---- prologue: tile0 (all 4 groups) + tile1 (Ag0,Bg0,Bg1) = 14 loads ----
    STAGE(0, 0, 0, 0); STAGE(1, 0, 0, 0); STAGE(1, 0, 1, 0); STAGE(0, 0, 1, 0);
    STAGE(0, 1, 0, 1); STAGE(1, 1, 0, 1); STAGE(1, 1, 1, 1);
    asm volatile("s_waitcnt vmcnt(6)" ::: "memory");   // tile0 complete
    BAR();

    // ---- steady iterations: tiles (2i, 2i+1), prefetch (2i+2, 2i+3) ----
    for (int i = 0; i < 3; ++i) {
        const int t1 = 2 * i + 1;
        // PH1: quad(0,0) of tile t0 (buf0)
        LOAD_A(0, 0); LOAD_B(0, 0);
        STAGE(0, 1, 1, t1);                    // buf1.Ag1 <- tile t1
        asm volatile("s_waitcnt lgkmcnt(8)");
        BAR(); LGKM0(); MFMA_Q(0, 0); BAR();
        // PH2: quad(0,1)
        LOAD_B(0, 1);
        STAGE(0, 0, 0, 2 * i + 2);             // buf0.Ag0 <- tile t0+2
        BAR(); LGKM0(); MFMA_Q(0, 1); BAR();
        // PH3: quad(1,1)
        LOAD_A(0, 1);
        STAGE(1, 0, 0, 2 * i + 2);             // buf0.Bg0
        BAR(); LGKM0(); MFMA_Q(1, 1); BAR();
        // PH4: quad(1,0) — vmcnt once per K-tile
        STAGE(1, 0, 1, 2 * i + 2);             // buf0.Bg1
        asm volatile("s_waitcnt vmcnt(6)" ::: "memory");   // tile t1 complete
        BAR(); MFMA_Q(1, 0); BAR();
        // PH5: quad(0,0) of tile t1 (buf1)
        LOAD_A(1, 0); LOAD_B(1, 0);
        STAGE(0, 0, 1, 2 * i + 2);             // buf0.Ag1
        asm volatile("s_waitcnt lgkmcnt(8)");
        BAR(); LGKM0(); MFMA_Q(0, 0); BAR();
        // PH6: quad(0,1)
        LOAD_B(1, 1);
        STAGE(0, 1, 0, 2 * i + 3);             // buf1.Ag0 <- tile t1+2
        BAR(); LGKM0(); MFMA_Q(0, 1); BAR();
        // PH7: quad(1,1)
        LOAD_A(1, 1);
        STAGE(1, 1, 0, 2 * i + 3);             // buf1.Bg0
        BAR(); LGKM0(); MFMA_Q(1, 1); BAR();
        // PH8: quad(1,0)
        STAGE(1, 1, 1, 2 * i + 3);             // buf1.Bg1
        asm volatile("s_waitcnt vmcnt(6)" ::: "memory");   // tile t0+2 complete
        BAR(); MFMA_Q(1, 0); BAR();
    }

    // ---- tail: tiles 6 (buf0) and 7 (buf1), no further prefetch ----
    LOAD_A(0, 0); LOAD_B(0, 0);
    STAGE(0, 1, 1, 7);                         // buf1.Ag1 <- tile 7 (last load)
    BAR(); LGKM0(); MFMA_Q(0, 0); BAR();
    LOAD_B(0, 1);
    BAR(); LGKM0(); MFMA_Q(0, 1); BAR();
    LOAD_A(0, 1);
    BAR(); LGKM0(); MFMA_Q(1, 1); BAR();
    asm volatile("s_waitcnt vmcnt(0)" ::: "memory");       // tile 7 complete
    BAR(); MFMA_Q(1, 0); BAR();
    LOAD_A(1, 0); LOAD_B(1, 0);
    BAR(); LGKM0(); MFMA_Q(0, 0); BAR();
    LOAD_B(1, 1);
    BAR(); LGKM0(); MFMA_Q(0, 1); BAR();
    LOAD_A(1, 1);
    BAR(); LGKM0(); MFMA_Q(1, 1); BAR();
    MFMA_Q(1, 0);

    // ---- epilogue: D mapping n = lane&15, m = (lane>>4)*4 + reg ----
    // NONTEMPORAL stores: C is 268 MB write-once data; keep it out of
    // L2/L3 so the bf16 operands stay cache-resident across rounds.
    const int r0 = q * 4;
    #pragma unroll
    for (int mi = 0; mi < 8; ++mi) {
        #pragma unroll
        for (int ni = 0; ni < 4; ++ni) {
            size_t base = (size_t)(tile_m + wm * 128 + mi * 16 + r0) * NROWS
                        + (size_t)(tile_n + wn * 64 + ni * 16 + fr);
            #pragma unroll
            for (int r = 0; r < 4; ++r)
                __builtin_nontemporal_store(acc[mi][ni][r],
                                            C + base + (size_t)r * NROWS);
        }
    }

#undef STAGE
#undef LOAD_A
#undef LOAD_B
#undef MFMA_Q
#undef BAR
#undef LGKM0
}

extern "C" void kernel_launch(void* const* d_in, const int* in_sizes, int n_in,
                              void* d_out, int out_size, void* d_ws, size_t ws_size,
                              hipStream_t stream) {
    const float* x1 = (const float*)d_in[0];
    const float* x2 = (const float*)d_in[1];
    float* out = (float*)d_out;

    u16* a_bf = (u16*)d_ws;                          // 8 MB
    u16* b_bf = a_bf + (size_t)NROWS * KDIM;         // 8 MB

    norm_cast_kernel<<<4096, 256, 0, stream>>>(x1, x2, a_bf, b_bf);

    const int grid = (NROWS / 256) * (NROWS / 256);  // 1024
    gemm_bt_kernel<<<grid, 512, 0, stream>>>(a_bf, b_bf, out);
}

// Round 8
// 118.884 us; speedup vs baseline: 1.2864x; 1.1315x over previous
//
#include <hip/hip_runtime.h>

#define NROWS 8192
#define KDIM  512

typedef __attribute__((ext_vector_type(8))) short bf16x8;   // 8 bf16 = 4 VGPRs
typedef __attribute__((ext_vector_type(4))) float f32x4;

typedef unsigned int u32;
typedef unsigned short u16;

// ---- round-to-nearest-even f32 -> bf16 (bits) ----
__device__ __forceinline__ u16 f2bf(float f) {
    u32 u = __float_as_uint(f);
    u32 rounding = 0x7FFFu + ((u >> 16) & 1u);
    return (u16)((u + rounding) >> 16);
}

// ---- async global->LDS, 16B per lane (wave-uniform base + lane*16) ----
__device__ __forceinline__ void gload_lds16(const void* g, void* l) {
    __builtin_amdgcn_global_load_lds(
        (const __attribute__((address_space(1))) u32*)g,
        (__attribute__((address_space(3))) u32*)l,
        16, 0, 0);
}

// =====================================================================
// Kernel 1: row-normalize (f32) -> bf16 scaled by 4 (= sqrt(16), exact
// power of two so bf16 rounding is identical to unscaled).
// =====================================================================
__global__ __launch_bounds__(256) void norm_cast_kernel(
        const float* __restrict__ x1, const float* __restrict__ x2,
        u16* __restrict__ o1, u16* __restrict__ o2) {
    const int wave = threadIdx.x >> 6;
    const int lane = threadIdx.x & 63;
    int row = blockIdx.x * 4 + wave;          // 0..16383

    const float* src;
    u16* dst;
    if (row < NROWS) { src = x1 + (size_t)row * KDIM;           dst = o1 + (size_t)row * KDIM; }
    else             { src = x2 + (size_t)(row - NROWS) * KDIM; dst = o2 + (size_t)(row - NROWS) * KDIM; }

    const float4* s4 = (const float4*)src + lane * 2;
    float4 a = s4[0];
    float4 b = s4[1];

    float ss = a.x*a.x + a.y*a.y + a.z*a.z + a.w*a.w
             + b.x*b.x + b.y*b.y + b.z*b.z + b.w*b.w;
    #pragma unroll
    for (int off = 32; off; off >>= 1) ss += __shfl_xor(ss, off);

    float inv = 4.0f / fmaxf(sqrtf(ss), 1e-8f);

    u16 h[8];
    h[0] = f2bf(a.x * inv); h[1] = f2bf(a.y * inv);
    h[2] = f2bf(a.z * inv); h[3] = f2bf(a.w * inv);
    h[4] = f2bf(b.x * inv); h[5] = f2bf(b.y * inv);
    h[6] = f2bf(b.z * inv); h[7] = f2bf(b.w * inv);

    uint4 o;
    o.x = (u32)h[0] | ((u32)h[1] << 16);
    o.y = (u32)h[2] | ((u32)h[3] << 16);
    o.z = (u32)h[4] | ((u32)h[5] << 16);
    o.w = (u32)h[6] | ((u32)h[7] << 16);
    *((uint4*)dst + lane) = o;
}

// =====================================================================
// Kernel 2: R2-verified 256x256 tile, BK=64, 8 waves (2Mx4N), 8-phase
// schedule, counted vmcnt(6), st XOR-swizzle, setprio, NORMAL stores.
// ONLY change vs R2: concurrency-aware 2D XCD swizzle. Each XCD's 32
// concurrently-resident blocks (bid%8==xcd, same round bid>>8) cover a
// 4 m-panel x 8 n-panel region: A 1MB + B 2MB = 3MB < 4MB L2 -> all
// intra-round staging is L2-hit; A panels fixed per XCD across rounds.
// =====================================================================

__global__ __launch_bounds__(512, 2) void gemm_bt_kernel(
        const u16* __restrict__ A, const u16* __restrict__ B,
        float* __restrict__ C) {
    __shared__ __align__(1024) char lds[131072];

    // 2D concurrency-aware XCD swizzle (grid must be 1024)
    const int bid = blockIdx.x;
    const int xcd = bid & 7;           // dispatch round-robins XCDs (m09)
    const int rnd = bid >> 8;          // 0..3 occupancy rounds (1 block/CU)
    const int s   = (bid >> 3) & 31;   // slot within (xcd, round)
    const int tile_m = (4 * xcd + (s >> 3)) << 8;   // m-panel 0..31
    const int tile_n = (8 * rnd + (s & 7)) << 8;    // n-panel 0..31

    const int tid  = threadIdx.x;
    const int wid  = tid >> 6;
    const int lane = tid & 63;
    const int wm   = wid >> 2;      // 0..1  (M)
    const int wn   = wid & 3;       // 0..3  (N)
    const int fr   = lane & 15;
    const int q    = lane >> 4;

    // staging constants: thread tid covers LDS bytes it*8192 + tid*16
    const int s_rl0 = tid >> 3;           // 0..63
    const int s_cl  = (tid & 7) << 4;     // 0..112

    // ds-read constants
    const int xr     = (fr & 7) << 4;
    const int colsw0 = (q * 16) ^ xr;          // kk=0 fragment col (swizzled)
    const int colsw1 = (64 + q * 16) ^ xr;     // kk=1
    const int aRow   = ((wm << 7) + fr) << 7;            // byte row base in A region
    const int bRow   = (((wn << 6) + fr) << 7) + 32768;  // byte row base in B region

    f32x4  acc[8][4] = {};
    bf16x8 af[4][2];   // current A half (4 mi x 2 kk)
    bf16x8 bf[4][2];   // full B tile   (4 ni x 2 kk)

// stage one half-group: ISB selects A/B, BUF buffer, G group bit, T K-tile idx
#define STAGE(ISB, BUF, G, T) do {                                             \
    const u16* _g  = (ISB) ? B : A;                                            \
    const int _grow = (ISB) ? tile_n : tile_m;                                 \
    char* _l = lds + (BUF) * 65536 + ((ISB) ? 32768 : 0);                      \
    _Pragma("unroll")                                                          \
    for (int _it = 0; _it < 2; ++_it) {                                        \
        int _rl  = _it * 64 + s_rl0;                                           \
        int _row = (ISB) ? (((_rl >> 5) << 6) + ((G) << 5) + (_rl & 31))       \
                         : (((_rl >> 6) << 7) + ((G) << 6) + (_rl & 63));      \
        int _csrc = s_cl ^ ((_row & 7) << 4);                                  \
        gload_lds16((const char*)_g + ((size_t)(_grow + _row) * KDIM + (size_t)(T) * 64) * 2 + _csrc, \
                    _l + _row * 128 + s_cl);                                   \
    }                                                                          \
} while (0)

#define LOAD_A(BUF, MH) do {                                                   \
    char* _l = lds + (BUF) * 65536;                                            \
    _Pragma("unroll")                                                          \
    for (int _m = 0; _m < 4; ++_m) {                                           \
        af[_m][0] = *(const bf16x8*)(_l + aRow + ((MH) * 4 + _m) * 2048 + colsw0); \
        af[_m][1] = *(const bf16x8*)(_l + aRow + ((MH) * 4 + _m) * 2048 + colsw1); \
    }                                                                          \
} while (0)

#define LOAD_B(BUF, NH) do {                                                   \
    char* _l = lds + (BUF) * 65536;                                            \
    _Pragma("unroll")                                                          \
    for (int _n = 0; _n < 2; ++_n) {                                           \
        bf[(NH) * 2 + _n][0] = *(const bf16x8*)(_l + bRow + ((NH) * 2 + _n) * 2048 + colsw0); \
        bf[(NH) * 2 + _n][1] = *(const bf16x8*)(_l + bRow + ((NH) * 2 + _n) * 2048 + colsw1); \
    }                                                                          \
} while (0)

#define MFMA_Q(MH, NH) do {                                                    \
    __builtin_amdgcn_s_setprio(1);                                             \
    _Pragma("unroll")                                                          \
    for (int _m = 0; _m < 4; ++_m)                                             \
    _Pragma("unroll")                                                          \
    for (int _n = 0; _n < 2; ++_n)                                             \
    _Pragma("unroll")                                                          \
    for (int _kk = 0; _kk < 2; ++_kk)                                          \
        acc[(MH) * 4 + _m][(NH) * 2 + _n] = __builtin_amdgcn_mfma_f32_16x16x32_bf16( \
            af[_m][_kk], bf[(NH) * 2 + _n][_kk], acc[(MH) * 4 + _m][(NH) * 2 + _n], 0, 0, 0); \
    __builtin_amdgcn_s_setprio(0);                                             \
} while (0)

#define BAR()   __builtin_amdgcn_s_barrier()
#define LGKM0() asm volatile("s_waitcnt lgkmcnt(0)")

    // ---- prologue: tile0 (all 4 groups) + tile1 (Ag0,Bg0,Bg1) = 14 loads ----
    STAGE(0, 0, 0, 0); STAGE(1, 0, 0, 0); STAGE(1, 0, 1, 0); STAGE(0, 0, 1, 0);
    STAGE(0, 1, 0, 1); STAGE(1, 1, 0, 1); STAGE(1, 1, 1, 1);
    asm volatile("s_waitcnt vmcnt(6)" ::: "memory");   // tile0 complete
    BAR();

    // ---- steady iterations: tiles (2i, 2i+1), prefetch (2i+2, 2i+3) ----
    for (int i = 0; i < 3; ++i) {
        const int t1 = 2 * i + 1;
        // PH1: quad(0,0) of tile t0 (buf0)
        LOAD_A(0, 0); LOAD_B(0, 0);
        STAGE(0, 1, 1, t1);                    // buf1.Ag1 <- tile t1
        asm volatile("s_waitcnt lgkmcnt(8)");
        BAR(); LGKM0(); MFMA_Q(0, 0); BAR();
        // PH2: quad(0,1)
        LOAD_B(0, 1);
        STAGE(0, 0, 0, 2 * i + 2);             // buf0.Ag0 <- tile t0+2
        BAR(); LGKM0(); MFMA_Q(0, 1); BAR();
        // PH3: quad(1,1)
        LOAD_A(0, 1);
        STAGE(1, 0, 0, 2 * i + 2);             // buf0.Bg0
        BAR(); LGKM0(); MFMA_Q(1, 1); BAR();
        // PH4: quad(1,0) — vmcnt once per K-tile
        STAGE(1, 0, 1, 2 * i + 2);             // buf0.Bg1
        asm volatile("s_waitcnt vmcnt(6)" ::: "memory");   // tile t1 complete
        BAR(); MFMA_Q(1, 0); BAR();
        // PH5: quad(0,0) of tile t1 (buf1)
        LOAD_A(1, 0); LOAD_B(1, 0);
        STAGE(0, 0, 1, 2 * i + 2);             // buf0.Ag1
        asm volatile("s_waitcnt lgkmcnt(8)");
        BAR(); LGKM0(); MFMA_Q(0, 0); BAR();
        // PH6: quad(0,1)
        LOAD_B(1, 1);
        STAGE(0, 1, 0, 2 * i + 3);             // buf1.Ag0 <- tile t1+2
        BAR(); LGKM0(); MFMA_Q(0, 1); BAR();
        // PH7: quad(1,1)
        LOAD_A(1, 1);
        STAGE(1, 1, 0, 2 * i + 3);             // buf1.Bg0
        BAR(); LGKM0(); MFMA_Q(1, 1); BAR();
        // PH8: quad(1,0)
        STAGE(1, 1, 1, 2 * i + 3);             // buf1.Bg1
        asm volatile("s_waitcnt vmcnt(6)" ::: "memory");   // tile t0+2 complete
        BAR(); MFMA_Q(1, 0); BAR();
    }

    // ---- tail: tiles 6 (buf0) and 7 (buf1), no further prefetch ----
    LOAD_A(0, 0); LOAD_B(0, 0);
    STAGE(0, 1, 1, 7);                         // buf1.Ag1 <- tile 7 (last load)
    BAR(); LGKM0(); MFMA_Q(0, 0); BAR();
    LOAD_B(0, 1);
    BAR(); LGKM0(); MFMA_Q(0, 1); BAR();
    LOAD_A(0, 1);
    BAR(); LGKM0(); MFMA_Q(1, 1); BAR();
    asm volatile("s_waitcnt vmcnt(0)" ::: "memory");       // tile 7 complete
    BAR(); MFMA_Q(1, 0); BAR();
    LOAD_A(1, 0); LOAD_B(1, 0);
    BAR(); LGKM0(); MFMA_Q(0, 0); BAR();
    LOAD_B(1, 1);
    BAR(); LGKM0(); MFMA_Q(0, 1); BAR();
    LOAD_A(1, 1);
    BAR(); LGKM0(); MFMA_Q(1, 1); BAR();
    MFMA_Q(1, 0);

    // ---- epilogue: D mapping n = lane&15, m = (lane>>4)*4 + reg ----
    // (scale pre-folded into the bf16 rows: 4 x 4 = 16)
    const int r0 = q * 4;
    #pragma unroll
    for (int mi = 0; mi < 8; ++mi) {
        #pragma unroll
        for (int ni = 0; ni < 4; ++ni) {
            size_t base = (size_t)(tile_m + wm * 128 + mi * 16 + r0) * NROWS
                        + (size_t)(tile_n + wn * 64 + ni * 16 + fr);
            #pragma unroll
            for (int r = 0; r < 4; ++r)
                C[base + (size_t)r * NROWS] = acc[mi][ni][r];
        }
    }

#undef STAGE
#undef LOAD_A
#undef LOAD_B
#undef MFMA_Q
#undef BAR
#undef LGKM0
}

extern "C" void kernel_launch(void* const* d_in, const int* in_sizes, int n_in,
                              void* d_out, int out_size, void* d_ws, size_t ws_size,
                              hipStream_t stream) {
    const float* x1 = (const float*)d_in[0];
    const float* x2 = (const float*)d_in[1];
    float* out = (float*)d_out;

    u16* a_bf = (u16*)d_ws;                          // 8 MB
    u16* b_bf = a_bf + (size_t)NROWS * KDIM;         // 8 MB

    norm_cast_kernel<<<4096, 256, 0, stream>>>(x1, x2, a_bf, b_bf);

    const int grid = (NROWS / 256) * (NROWS / 256);  // 1024
    gemm_bt_kernel<<<grid, 512, 0, stream>>>(a_bf, b_bf, out);
}

// Round 9
// 117.031 us; speedup vs baseline: 1.3068x; 1.0158x over previous
//
#include <hip/hip_runtime.h>

#define NROWS 8192
#define KDIM  512

typedef __attribute__((ext_vector_type(8))) short bf16x8;   // 8 bf16 = 4 VGPRs
typedef __attribute__((ext_vector_type(4))) float f32x4;

typedef unsigned int u32;
typedef unsigned short u16;

// ---- round-to-nearest-even f32 -> bf16 (bits) ----
__device__ __forceinline__ u16 f2bf(float f) {
    u32 u = __float_as_uint(f);
    u32 rounding = 0x7FFFu + ((u >> 16) & 1u);
    return (u16)((u + rounding) >> 16);
}

// ---- async global->LDS, 16B per lane (wave-uniform base + lane*16) ----
__device__ __forceinline__ void gload_lds16(const void* g, void* l) {
    __builtin_amdgcn_global_load_lds(
        (const __attribute__((address_space(1))) u32*)g,
        (__attribute__((address_space(3))) u32*)l,
        16, 0, 0);
}

// =====================================================================
// Kernel 1: row-normalize (f32) -> bf16 scaled by 4 (= sqrt(16), exact
// power of two so bf16 rounding is identical to unscaled).
// =====================================================================
__global__ __launch_bounds__(256) void norm_cast_kernel(
        const float* __restrict__ x1, const float* __restrict__ x2,
        u16* __restrict__ o1, u16* __restrict__ o2) {
    const int wave = threadIdx.x >> 6;
    const int lane = threadIdx.x & 63;
    int row = blockIdx.x * 4 + wave;          // 0..16383

    const float* src;
    u16* dst;
    if (row < NROWS) { src = x1 + (size_t)row * KDIM;           dst = o1 + (size_t)row * KDIM; }
    else             { src = x2 + (size_t)(row - NROWS) * KDIM; dst = o2 + (size_t)(row - NROWS) * KDIM; }

    const float4* s4 = (const float4*)src + lane * 2;
    float4 a = s4[0];
    float4 b = s4[1];

    float ss = a.x*a.x + a.y*a.y + a.z*a.z + a.w*a.w
             + b.x*b.x + b.y*b.y + b.z*b.z + b.w*b.w;
    #pragma unroll
    for (int off = 32; off; off >>= 1) ss += __shfl_xor(ss, off);

    float inv = 4.0f / fmaxf(sqrtf(ss), 1e-8f);

    u16 h[8];
    h[0] = f2bf(a.x * inv); h[1] = f2bf(a.y * inv);
    h[2] = f2bf(a.z * inv); h[3] = f2bf(a.w * inv);
    h[4] = f2bf(b.x * inv); h[5] = f2bf(b.y * inv);
    h[6] = f2bf(b.z * inv); h[7] = f2bf(b.w * inv);

    uint4 o;
    o.x = (u32)h[0] | ((u32)h[1] << 16);
    o.y = (u32)h[2] | ((u32)h[3] << 16);
    o.z = (u32)h[4] | ((u32)h[5] << 16);
    o.w = (u32)h[6] | ((u32)h[7] << 16);
    *((uint4*)dst + lane) = o;
}

// =====================================================================
// Kernel 2: R2-verified 256x256 tile, BK=64, 8 waves (2Mx4N), 8-phase
// schedule, counted vmcnt(6), st XOR-swizzle, setprio, chunked bijective
// XCD swizzle, normal stores. (Best measured config: 116 us total.)
// Scale pre-folded into the bf16 rows (4 per side -> 16 total).
// =====================================================================

__global__ __launch_bounds__(512, 2) void gemm_bt_kernel(
        const u16* __restrict__ A, const u16* __restrict__ B,
        float* __restrict__ C) {
    __shared__ __align__(1024) char lds[131072];

    // bijective XCD swizzle (nwg = 1024, divisible by 8)
    const int nwg = gridDim.x;
    const int bid = blockIdx.x;
    const int wg  = (bid & 7) * (nwg >> 3) + (bid >> 3);
    const int tile_m = (wg >> 5) << 8;
    const int tile_n = (wg & 31) << 8;

    const int tid  = threadIdx.x;
    const int wid  = tid >> 6;
    const int lane = tid & 63;
    const int wm   = wid >> 2;      // 0..1  (M)
    const int wn   = wid & 3;       // 0..3  (N)
    const int fr   = lane & 15;
    const int q    = lane >> 4;

    // staging constants: thread tid covers LDS bytes it*8192 + tid*16
    const int s_rl0 = tid >> 3;           // 0..63
    const int s_cl  = (tid & 7) << 4;     // 0..112

    // ds-read constants
    const int xr     = (fr & 7) << 4;
    const int colsw0 = (q * 16) ^ xr;          // kk=0 fragment col (swizzled)
    const int colsw1 = (64 + q * 16) ^ xr;     // kk=1
    const int aRow   = ((wm << 7) + fr) << 7;            // byte row base in A region
    const int bRow   = (((wn << 6) + fr) << 7) + 32768;  // byte row base in B region

    f32x4  acc[8][4] = {};
    bf16x8 af[4][2];   // current A half (4 mi x 2 kk)
    bf16x8 bf[4][2];   // full B tile   (4 ni x 2 kk)

// stage one half-group: ISB selects A/B, BUF buffer, G group bit, T K-tile idx
#define STAGE(ISB, BUF, G, T) do {                                             \
    const u16* _g  = (ISB) ? B : A;                                            \
    const int _grow = (ISB) ? tile_n : tile_m;                                 \
    char* _l = lds + (BUF) * 65536 + ((ISB) ? 32768 : 0);                      \
    _Pragma("unroll")                                                          \
    for (int _it = 0; _it < 2; ++_it) {                                        \
        int _rl  = _it * 64 + s_rl0;                                           \
        int _row = (ISB) ? (((_rl >> 5) << 6) + ((G) << 5) + (_rl & 31))       \
                         : (((_rl >> 6) << 7) + ((G) << 6) + (_rl & 63));      \
        int _csrc = s_cl ^ ((_row & 7) << 4);                                  \
        gload_lds16((const char*)_g + ((size_t)(_grow + _row) * KDIM + (size_t)(T) * 64) * 2 + _csrc, \
                    _l + _row * 128 + s_cl);                                   \
    }                                                                          \
} while (0)

#define LOAD_A(BUF, MH) do {                                                   \
    char* _l = lds + (BUF) * 65536;                                            \
    _Pragma("unroll")                                                          \
    for (int _m = 0; _m < 4; ++_m) {                                           \
        af[_m][0] = *(const bf16x8*)(_l + aRow + ((MH) * 4 + _m) * 2048 + colsw0); \
        af[_m][1] = *(const bf16x8*)(_l + aRow + ((MH) * 4 + _m) * 2048 + colsw1); \
    }                                                                          \
} while (0)

#define LOAD_B(BUF, NH) do {                                                   \
    char* _l = lds + (BUF) * 65536;                                            \
    _Pragma("unroll")                                                          \
    for (int _n = 0; _n < 2; ++_n) {                                           \
        bf[(NH) * 2 + _n][0] = *(const bf16x8*)(_l + bRow + ((NH) * 2 + _n) * 2048 + colsw0); \
        bf[(NH) * 2 + _n][1] = *(const bf16x8*)(_l + bRow + ((NH) * 2 + _n) * 2048 + colsw1); \
    }                                                                          \
} while (0)

#define MFMA_Q(MH, NH) do {                                                    \
    __builtin_amdgcn_s_setprio(1);                                             \
    _Pragma("unroll")                                                          \
    for (int _m = 0; _m < 4; ++_m)                                             \
    _Pragma("unroll")                                                          \
    for (int _n = 0; _n < 2; ++_n)                                             \
    _Pragma("unroll")                                                          \
    for (int _kk = 0; _kk < 2; ++_kk)                                          \
        acc[(MH) * 4 + _m][(NH) * 2 + _n] = __builtin_amdgcn_mfma_f32_16x16x32_bf16( \
            af[_m][_kk], bf[(NH) * 2 + _n][_kk], acc[(MH) * 4 + _m][(NH) * 2 + _n], 0, 0, 0); \
    __builtin_amdgcn_s_setprio(0);                                             \
} while (0)

#define BAR()   __builtin_amdgcn_s_barrier()
#define LGKM0() asm volatile("s_waitcnt lgkmcnt(0)")

    // ---- prologue: tile0 (all 4 groups) + tile1 (Ag0,Bg0,Bg1) = 14 loads ----
    STAGE(0, 0, 0, 0); STAGE(1, 0, 0, 0); STAGE(1, 0, 1, 0); STAGE(0, 0, 1, 0);
    STAGE(0, 1, 0, 1); STAGE(1, 1, 0, 1); STAGE(1, 1, 1, 1);
    asm volatile("s_waitcnt vmcnt(6)" ::: "memory");   // tile0 complete
    BAR();

    // ---- steady iterations: tiles (2i, 2i+1), prefetch (2i+2, 2i+3) ----
    for (int i = 0; i < 3; ++i) {
        const int t1 = 2 * i + 1;
        // PH1: quad(0,0) of tile t0 (buf0)
        LOAD_A(0, 0); LOAD_B(0, 0);
        STAGE(0, 1, 1, t1);                    // buf1.Ag1 <- tile t1
        asm volatile("s_waitcnt lgkmcnt(8)");
        BAR(); LGKM0(); MFMA_Q(0, 0); BAR();
        // PH2: quad(0,1)
        LOAD_B(0, 1);
        STAGE(0, 0, 0, 2 * i + 2);             // buf0.Ag0 <- tile t0+2
        BAR(); LGKM0(); MFMA_Q(0, 1); BAR();
        // PH3: quad(1,1)
        LOAD_A(0, 1);
        STAGE(1, 0, 0, 2 * i + 2);             // buf0.Bg0
        BAR(); LGKM0(); MFMA_Q(1, 1); BAR();
        // PH4: quad(1,0) — vmcnt once per K-tile
        STAGE(1, 0, 1, 2 * i + 2);             // buf0.Bg1
        asm volatile("s_waitcnt vmcnt(6)" ::: "memory");   // tile t1 complete
        BAR(); MFMA_Q(1, 0); BAR();
        // PH5: quad(0,0) of tile t1 (buf1)
        LOAD_A(1, 0); LOAD_B(1, 0);
        STAGE(0, 0, 1, 2 * i + 2);             // buf0.Ag1
        asm volatile("s_waitcnt lgkmcnt(8)");
        BAR(); LGKM0(); MFMA_Q(0, 0); BAR();
        // PH6: quad(0,1)
        LOAD_B(1, 1);
        STAGE(0, 1, 0, 2 * i + 3);             // buf1.Ag0 <- tile t1+2
        BAR(); LGKM0(); MFMA_Q(0, 1); BAR();
        // PH7: quad(1,1)
        LOAD_A(1, 1);
        STAGE(1, 1, 0, 2 * i + 3);             // buf1.Bg0
        BAR(); LGKM0(); MFMA_Q(1, 1); BAR();
        // PH8: quad(1,0)
        STAGE(1, 1, 1, 2 * i + 3);             // buf1.Bg1
        asm volatile("s_waitcnt vmcnt(6)" ::: "memory");   // tile t0+2 complete
        BAR(); MFMA_Q(1, 0); BAR();
    }

    // ---- tail: tiles 6 (buf0) and 7 (buf1), no further prefetch ----
    LOAD_A(0, 0); LOAD_B(0, 0);
    STAGE(0, 1, 1, 7);                         // buf1.Ag1 <- tile 7 (last load)
    BAR(); LGKM0(); MFMA_Q(0, 0); BAR();
    LOAD_B(0, 1);
    BAR(); LGKM0(); MFMA_Q(0, 1); BAR();
    LOAD_A(0, 1);
    BAR(); LGKM0(); MFMA_Q(1, 1); BAR();
    asm volatile("s_waitcnt vmcnt(0)" ::: "memory");       // tile 7 complete
    BAR(); MFMA_Q(1, 0); BAR();
    LOAD_A(1, 0); LOAD_B(1, 0);
    BAR(); LGKM0(); MFMA_Q(0, 0); BAR();
    LOAD_B(1, 1);
    BAR(); LGKM0(); MFMA_Q(0, 1); BAR();
    LOAD_A(1, 1);
    BAR(); LGKM0(); MFMA_Q(1, 1); BAR();
    MFMA_Q(1, 0);

    // ---- epilogue: D mapping n = lane&15, m = (lane>>4)*4 + reg ----
    // (scale pre-folded into the bf16 rows: 4 x 4 = 16)
    const int r0 = q * 4;
    #pragma unroll
    for (int mi = 0; mi < 8; ++mi) {
        #pragma unroll
        for (int ni = 0; ni < 4; ++ni) {
            size_t base = (size_t)(tile_m + wm * 128 + mi * 16 + r0) * NROWS
                        + (size_t)(tile_n + wn * 64 + ni * 16 + fr);
            #pragma unroll
            for (int r = 0; r < 4; ++r)
                C[base + (size_t)r * NROWS] = acc[mi][ni][r];
        }
    }

#undef STAGE
#undef LOAD_A
#undef LOAD_B
#undef MFMA_Q
#undef BAR
#undef LGKM0
}

extern "C" void kernel_launch(void* const* d_in, const int* in_sizes, int n_in,
                              void* d_out, int out_size, void* d_ws, size_t ws_size,
                              hipStream_t stream) {
    const float* x1 = (const float*)d_in[0];
    const float* x2 = (const float*)d_in[1];
    float* out = (float*)d_out;

    u16* a_bf = (u16*)d_ws;                          // 8 MB
    u16* b_bf = a_bf + (size_t)NROWS * KDIM;         // 8 MB

    norm_cast_kernel<<<4096, 256, 0, stream>>>(x1, x2, a_bf, b_bf);

    const int grid = (NROWS / 256) * (NROWS / 256);  // 1024
    gemm_bt_kernel<<<grid, 512, 0, stream>>>(a_bf, b_bf, out);
}

// Round 10
// 115.255 us; speedup vs baseline: 1.3269x; 1.0154x over previous
//
#include <hip/hip_runtime.h>

#define NROWS 8192
#define KDIM  512

typedef __attribute__((ext_vector_type(8))) short bf16x8;   // 8 bf16 = 4 VGPRs
typedef __attribute__((ext_vector_type(4))) float f32x4;

typedef unsigned int u32;
typedef unsigned short u16;

// ---- round-to-nearest-even f32 -> bf16 (bits) ----
__device__ __forceinline__ u16 f2bf(float f) {
    u32 u = __float_as_uint(f);
    u32 rounding = 0x7FFFu + ((u >> 16) & 1u);
    return (u16)((u + rounding) >> 16);
}

// ---- async global->LDS, 16B per lane (wave-uniform base + lane*16) ----
__device__ __forceinline__ void gload_lds16(const void* g, void* l) {
    __builtin_amdgcn_global_load_lds(
        (const __attribute__((address_space(1))) u32*)g,
        (__attribute__((address_space(3))) u32*)l,
        16, 0, 0);
}

// =====================================================================
// Kernel 1: row-normalize (f32) -> bf16 scaled by 4 (= sqrt(16), exact
// power of two so bf16 rounding is identical to unscaled).
// =====================================================================
__global__ __launch_bounds__(256) void norm_cast_kernel(
        const float* __restrict__ x1, const float* __restrict__ x2,
        u16* __restrict__ o1, u16* __restrict__ o2) {
    const int wave = threadIdx.x >> 6;
    const int lane = threadIdx.x & 63;
    int row = blockIdx.x * 4 + wave;          // 0..16383

    const float* src;
    u16* dst;
    if (row < NROWS) { src = x1 + (size_t)row * KDIM;           dst = o1 + (size_t)row * KDIM; }
    else             { src = x2 + (size_t)(row - NROWS) * KDIM; dst = o2 + (size_t)(row - NROWS) * KDIM; }

    const float4* s4 = (const float4*)src + lane * 2;
    float4 a = s4[0];
    float4 b = s4[1];

    float ss = a.x*a.x + a.y*a.y + a.z*a.z + a.w*a.w
             + b.x*b.x + b.y*b.y + b.z*b.z + b.w*b.w;
    #pragma unroll
    for (int off = 32; off; off >>= 1) ss += __shfl_xor(ss, off);

    float inv = 4.0f / fmaxf(sqrtf(ss), 1e-8f);

    u16 h[8];
    h[0] = f2bf(a.x * inv); h[1] = f2bf(a.y * inv);
    h[2] = f2bf(a.z * inv); h[3] = f2bf(a.w * inv);
    h[4] = f2bf(b.x * inv); h[5] = f2bf(b.y * inv);
    h[6] = f2bf(b.z * inv); h[7] = f2bf(b.w * inv);

    uint4 o;
    o.x = (u32)h[0] | ((u32)h[1] << 16);
    o.y = (u32)h[2] | ((u32)h[3] << 16);
    o.z = (u32)h[4] | ((u32)h[5] << 16);
    o.w = (u32)h[6] | ((u32)h[7] << 16);
    *((uint4*)dst + lane) = o;
}

// =====================================================================
// Kernel 2: R2-verified 256x256 tile / BK=64 / 8 waves / 8-phase counted
// vmcnt(6) core (unchanged). New:
//  - R8 2D concurrency swizzle: per-XCD concurrent working set
//    A 1MB + B 2.1MB < 4MB L2.
//  - Epilogue: per-wave LDS transpose (2 passes x 16KB/wave, LDS dead
//    after K-loop) so each 16-lane group stores 256B contiguous f32x4
//    FULL LINES via nontemporal stores -> C stream exits L2 evict-first
//    without partial-line RMW and without evicting the staged inputs.
// =====================================================================

__global__ __launch_bounds__(512, 2) void gemm_bt_kernel(
        const u16* __restrict__ A, const u16* __restrict__ B,
        float* __restrict__ C) {
    __shared__ __align__(1024) char lds[131072];

    // 2D concurrency-aware XCD swizzle (grid = 1024)
    const int bid = blockIdx.x;
    const int xcd = bid & 7;           // dispatch round-robins XCDs
    const int rnd = bid >> 8;          // 0..3 occupancy rounds (1 block/CU)
    const int s   = (bid >> 3) & 31;   // slot within (xcd, round)
    const int tile_m = (4 * xcd + (s >> 3)) << 8;   // m-panel 0..31
    const int tile_n = (8 * rnd + (s & 7)) << 8;    // n-panel 0..31

    const int tid  = threadIdx.x;
    const int wid  = tid >> 6;
    const int lane = tid & 63;
    const int wm   = wid >> 2;      // 0..1  (M)
    const int wn   = wid & 3;       // 0..3  (N)
    const int fr   = lane & 15;
    const int q    = lane >> 4;

    // staging constants: thread tid covers LDS bytes it*8192 + tid*16
    const int s_rl0 = tid >> 3;           // 0..63
    const int s_cl  = (tid & 7) << 4;     // 0..112

    // ds-read constants
    const int xr     = (fr & 7) << 4;
    const int colsw0 = (q * 16) ^ xr;          // kk=0 fragment col (swizzled)
    const int colsw1 = (64 + q * 16) ^ xr;     // kk=1
    const int aRow   = ((wm << 7) + fr) << 7;            // byte row base in A region
    const int bRow   = (((wn << 6) + fr) << 7) + 32768;  // byte row base in B region

    f32x4  acc[8][4] = {};
    bf16x8 af[4][2];   // current A half (4 mi x 2 kk)
    bf16x8 bf[4][2];   // full B tile   (4 ni x 2 kk)

// stage one half-group: ISB selects A/B, BUF buffer, G group bit, T K-tile idx
#define STAGE(ISB, BUF, G, T) do {                                             \
    const u16* _g  = (ISB) ? B : A;                                            \
    const int _grow = (ISB) ? tile_n : tile_m;                                 \
    char* _l = lds + (BUF) * 65536 + ((ISB) ? 32768 : 0);                      \
    _Pragma("unroll")                                                          \
    for (int _it = 0; _it < 2; ++_it) {                                        \
        int _rl  = _it * 64 + s_rl0;                                           \
        int _row = (ISB) ? (((_rl >> 5) << 6) + ((G) << 5) + (_rl & 31))       \
                         : (((_rl >> 6) << 7) + ((G) << 6) + (_rl & 63));      \
        int _csrc = s_cl ^ ((_row & 7) << 4);                                  \
        gload_lds16((const char*)_g + ((size_t)(_grow + _row) * KDIM + (size_t)(T) * 64) * 2 + _csrc, \
                    _l + _row * 128 + s_cl);                                   \
    }                                                                          \
} while (0)

#define LOAD_A(BUF, MH) do {                                                   \
    char* _l = lds + (BUF) * 65536;                                            \
    _Pragma("unroll")                                                          \
    for (int _m = 0; _m < 4; ++_m) {                                           \
        af[_m][0] = *(const bf16x8*)(_l + aRow + ((MH) * 4 + _m) * 2048 + colsw0); \
        af[_m][1] = *(const bf16x8*)(_l + aRow + ((MH) * 4 + _m) * 2048 + colsw1); \
    }                                                                          \
} while (0)

#define LOAD_B(BUF, NH) do {                                                   \
    char* _l = lds + (BUF) * 65536;                                            \
    _Pragma("unroll")                                                          \
    for (int _n = 0; _n < 2; ++_n) {                                           \
        bf[(NH) * 2 + _n][0] = *(const bf16x8*)(_l + bRow + ((NH) * 2 + _n) * 2048 + colsw0); \
        bf[(NH) * 2 + _n][1] = *(const bf16x8*)(_l + bRow + ((NH) * 2 + _n) * 2048 + colsw1); \
    }                                                                          \
} while (0)

#define MFMA_Q(MH, NH) do {                                                    \
    __builtin_amdgcn_s_setprio(1);                                             \
    _Pragma("unroll")                                                          \
    for (int _m = 0; _m < 4; ++_m)                                             \
    _Pragma("unroll")                                                          \
    for (int _n = 0; _n < 2; ++_n)                                             \
    _Pragma("unroll")                                                          \
    for (int _kk = 0; _kk < 2; ++_kk)                                          \
        acc[(MH) * 4 + _m][(NH) * 2 + _n] = __builtin_amdgcn_mfma_f32_16x16x32_bf16( \
            af[_m][_kk], bf[(NH) * 2 + _n][_kk], acc[(MH) * 4 + _m][(NH) * 2 + _n], 0, 0, 0); \
    __builtin_amdgcn_s_setprio(0);                                             \
} while (0)

#define BAR()   __builtin_amdgcn_s_barrier()
#define LGKM0() asm volatile("s_waitcnt lgkmcnt(0)")

    // ---- prologue: tile0 (all 4 groups) + tile1 (Ag0,Bg0,Bg1) = 14 loads ----
    STAGE(0, 0, 0, 0); STAGE(1, 0, 0, 0); STAGE(1, 0, 1, 0); STAGE(0, 0, 1, 0);
    STAGE(0, 1, 0, 1); STAGE(1, 1, 0, 1); STAGE(1, 1, 1, 1);
    asm volatile("s_waitcnt vmcnt(6)" ::: "memory");   // tile0 complete
    BAR();

    // ---- steady iterations: tiles (2i, 2i+1), prefetch (2i+2, 2i+3) ----
    for (int i = 0; i < 3; ++i) {
        const int t1 = 2 * i + 1;
        // PH1: quad(0,0) of tile t0 (buf0)
        LOAD_A(0, 0); LOAD_B(0, 0);
        STAGE(0, 1, 1, t1);                    // buf1.Ag1 <- tile t1
        asm volatile("s_waitcnt lgkmcnt(8)");
        BAR(); LGKM0(); MFMA_Q(0, 0); BAR();
        // PH2: quad(0,1)
        LOAD_B(0, 1);
        STAGE(0, 0, 0, 2 * i + 2);             // buf0.Ag0 <- tile t0+2
        BAR(); LGKM0(); MFMA_Q(0, 1); BAR();
        // PH3: quad(1,1)
        LOAD_A(0, 1);
        STAGE(1, 0, 0, 2 * i + 2);             // buf0.Bg0
        BAR(); LGKM0(); MFMA_Q(1, 1); BAR();
        // PH4: quad(1,0) — vmcnt once per K-tile
        STAGE(1, 0, 1, 2 * i + 2);             // buf0.Bg1
        asm volatile("s_waitcnt vmcnt(6)" ::: "memory");   // tile t1 complete
        BAR(); MFMA_Q(1, 0); BAR();
        // PH5: quad(0,0) of tile t1 (buf1)
        LOAD_A(1, 0); LOAD_B(1, 0);
        STAGE(0, 0, 1, 2 * i + 2);             // buf0.Ag1
        asm volatile("s_waitcnt lgkmcnt(8)");
        BAR(); LGKM0(); MFMA_Q(0, 0); BAR();
        // PH6: quad(0,1)
        LOAD_B(1, 1);
        STAGE(0, 1, 0, 2 * i + 3);             // buf1.Ag0 <- tile t1+2
        BAR(); LGKM0(); MFMA_Q(0, 1); BAR();
        // PH7: quad(1,1)
        LOAD_A(1, 1);
        STAGE(1, 1, 0, 2 * i + 3);             // buf1.Bg0
        BAR(); LGKM0(); MFMA_Q(1, 1); BAR();
        // PH8: quad(1,0)
        STAGE(1, 1, 1, 2 * i + 3);             // buf1.Bg1
        asm volatile("s_waitcnt vmcnt(6)" ::: "memory");   // tile t0+2 complete
        BAR(); MFMA_Q(1, 0); BAR();
    }

    // ---- tail: tiles 6 (buf0) and 7 (buf1), no further prefetch ----
    LOAD_A(0, 0); LOAD_B(0, 0);
    STAGE(0, 1, 1, 7);                         // buf1.Ag1 <- tile 7 (last load)
    BAR(); LGKM0(); MFMA_Q(0, 0); BAR();
    LOAD_B(0, 1);
    BAR(); LGKM0(); MFMA_Q(0, 1); BAR();
    LOAD_A(0, 1);
    BAR(); LGKM0(); MFMA_Q(1, 1); BAR();
    asm volatile("s_waitcnt vmcnt(0)" ::: "memory");       // tile 7 complete
    BAR(); MFMA_Q(1, 0); BAR();
    LOAD_A(1, 0); LOAD_B(1, 0);
    BAR(); LGKM0(); MFMA_Q(0, 0); BAR();
    LOAD_B(1, 1);
    BAR(); LGKM0(); MFMA_Q(0, 1); BAR();
    LOAD_A(1, 1);
    BAR(); LGKM0(); MFMA_Q(1, 1); BAR();
    MFMA_Q(1, 0);

    // =================================================================
    // Epilogue: LDS transpose -> full-line nontemporal stores.
    // Wave owns C rows [wm*128 + p*64 .. +63] x cols [wn*64 .. +63].
    // Pass p: scatter acc[4p..4p+3][*] into wave-private 16KB LDS
    // [m_loc 0..63][n_loc 0..63] f32 with 16B-chunk rotation
    // (chunk' = (chunk + m_loc) & 15), then each 16-lane group reads
    // one row (f32x4/lane) and nt-stores 256B contiguous.
    // =================================================================
    BAR();   // all waves done with K-loop LDS reads (lgkm0'd per wave)

    {
        char* wbase = lds + wid * 16384;
        #pragma unroll
        for (int p = 0; p < 2; ++p) {
            #pragma unroll
            for (int mi2 = 0; mi2 < 4; ++mi2) {
                #pragma unroll
                for (int ni = 0; ni < 4; ++ni) {
                    #pragma unroll
                    for (int r = 0; r < 4; ++r) {
                        const int m_loc = mi2 * 16 + q * 4 + r;
                        const int n_loc = ni * 16 + fr;
                        const int ch    = ((n_loc >> 2) + m_loc) & 15;
                        *(float*)(wbase + m_loc * 256 + ch * 16 + (n_loc & 3) * 4)
                            = acc[p * 4 + mi2][ni][r];
                    }
                }
            }
            asm volatile("s_waitcnt lgkmcnt(0)" ::: "memory");  // writes visible to own reads
            #pragma unroll
            for (int rr = 0; rr < 16; ++rr) {
                const int m_loc = rr * 4 + q;                  // q-interleave: even banks
                const int ch    = (fr + m_loc) & 15;
                f32x4 v = *(const f32x4*)(wbase + m_loc * 256 + ch * 16);
                __builtin_nontemporal_store(v,
                    (f32x4*)(C + (size_t)(tile_m + wm * 128 + p * 64 + m_loc) * NROWS
                               + tile_n + wn * 64 + fr * 4));
            }
            // pass-0 LDS reads must retire before pass-1 overwrites
            asm volatile("s_waitcnt lgkmcnt(0)" ::: "memory");
        }
    }

#undef STAGE
#undef LOAD_A
#undef LOAD_B
#undef MFMA_Q
#undef BAR
#undef LGKM0
}

extern "C" void kernel_launch(void* const* d_in, const int* in_sizes, int n_in,
                              void* d_out, int out_size, void* d_ws, size_t ws_size,
                              hipStream_t stream) {
    const float* x1 = (const float*)d_in[0];
    const float* x2 = (const float*)d_in[1];
    float* out = (float*)d_out;

    u16* a_bf = (u16*)d_ws;                          // 8 MB
    u16* b_bf = a_bf + (size_t)NROWS * KDIM;         // 8 MB

    norm_cast_kernel<<<4096, 256, 0, stream>>>(x1, x2, a_bf, b_bf);

    const int grid = (NROWS / 256) * (NROWS / 256);  // 1024
    gemm_bt_kernel<<<grid, 512, 0, stream>>>(a_bf, b_bf, out);
}